// Round 2
// baseline (301.476 us; speedup 1.0000x reference)
//
#include <hip/hip_runtime.h>
#include <math.h>

// QURNN cell, MI355X gfx950. Device tensors are FLOAT32 (per harness contract:
// dtype follows the reference, which is jnp.float32 everywhere).
// B=4096, D_IN=D_H=1024.
//
// GEMM precision strategy (no fp32 MFMA on CDNA4):
//  - Tr, Wt (feed the discrete `leap` branch): f16 2-way split (hi + residual),
//    3 MFMAs per tile-step (hh, hl, lh). Products exact in f32; error ~1e-7.
//  - Ei, Wa, Hw, Eh (continuous, damped by sigmoid/tanh): single f16 MFMA.
//
// Dispatches:
//  1) qurnn_gemm5: z in {Tr,Wt,Ei,Wa,Hw}, 128x128 tile, BK=32,
//     f32 global_load_lds staging with XOR involution swizzle (bank fix),
//     f32->f16(+lo) convert at fragment read, fused activation epilogue.
//  2) qurnn_cell : elementwise leap/time/excited/h_up (f32x4 vectorized).
//  3) qurnn_eh   : Eh GEMM on [input | h_up(f16)] + fused h_next epilogue.
//
// Buffer reuse: ratio -> out_time region (overwritten by cell),
//               absorb -> out_excited region, hw -> out_h region.
// ws (32MB): ut f32 [0,16M) | ei f16 [16M,24M) | hup f16 [24M,32M)

typedef __attribute__((ext_vector_type(4))) float f32x4;
typedef __attribute__((ext_vector_type(8))) _Float16 half8;
typedef __attribute__((ext_vector_type(4))) _Float16 half4;

#define NEL (4096 * 1024)

__device__ __forceinline__ float sigm(float x) { return 1.0f / (1.0f + expf(-x)); }

__device__ __forceinline__ void gload16(const void* g, void* l) {
  __builtin_amdgcn_global_load_lds(
      (const __attribute__((address_space(1))) void*)g,
      (__attribute__((address_space(3))) void*)l, 16, 0, 0);
}

// op: 0 sigmoid->f32, 1 tanh->f32, 2 sigmoid->f16, 3 h_next epilogue->f32
__device__ __forceinline__ void gemm_core(
    const float* A1, const float* A2f, const _Float16* A2h,
    const float* W, const float* bias, const int K,
    const bool split, const int op,
    float* outF, _Float16* outH, const float* hw_p, const float* hc_p)
{
  __shared__ __align__(16) float As[128 * 32];
  __shared__ __align__(16) float Bs[128 * 32];
  const int tid = threadIdx.x;
  const int lane = tid & 63;
  const int w = tid >> 6;
  const int wr = w >> 1, wc = w & 1;     // 2x2 waves, 64x64 tile each
  const int brow = blockIdx.x * 128;
  const int bcol = blockIdx.y * 128;
  const int lr = lane & 15;
  const int lq = lane >> 4;

  f32x4 acc[4][4] = {};

  for (int k0 = 0; k0 < K; k0 += 32) {
    const bool af16 = (A2h != nullptr) && (k0 >= 1024);
    __syncthreads();
    if (!af16) {
      const float* Ap = (k0 < 1024) ? A1 : A2f;
      const int kk = k0 & 1023;
#pragma unroll
      for (int i = 0; i < 4; ++i) {
        const int c = i * 256 + tid;        // LDS byte = c*16 (linear, lane-contig)
        const int row = c >> 3;
        const int kb = (c & 7) * 4;         // float offset in 32-float row
        const int src = kb ^ ((row & 7) << 2);  // involution swizzle (source side)
        gload16(Ap + (size_t)(brow + row) * 1024 + kk + src, &As[row * 32 + kb]);
      }
    } else {  // Eh second half: A = hup, native f16 tile
      const int kk = k0 - 1024;
      _Float16* Ash = (_Float16*)As;
#pragma unroll
      for (int i = 0; i < 2; ++i) {
        const int c = i * 256 + tid;
        const int row = c >> 2;
        const int hb = (c & 3) * 8;
        gload16(A2h + (size_t)(brow + row) * 1024 + kk + hb, Ash + row * 32 + hb);
      }
    }
#pragma unroll
    for (int i = 0; i < 4; ++i) {
      const int c = i * 256 + tid;
      const int row = c >> 3;
      const int kb = (c & 7) * 4;
      const int src = kb ^ ((row & 7) << 2);
      gload16(W + (size_t)(bcol + row) * K + k0 + src, &Bs[row * 32 + kb]);
    }
    __syncthreads();

    half8 ah[4], al[4], bh[4], bl[4];
#pragma unroll
    for (int m = 0; m < 4; ++m) {
      const int row = wr * 64 + m * 16 + lr;
      if (af16) {
        ah[m] = *(const half8*)&((const _Float16*)As)[row * 32 + lq * 8];
      } else {
        const int sw = (row & 7) << 2;      // same involution on the read side
        f32x4 v0 = *(const f32x4*)&As[row * 32 + ((lq * 8) ^ sw)];
        f32x4 v1 = *(const f32x4*)&As[row * 32 + ((lq * 8 + 4) ^ sw)];
#pragma unroll
        for (int j = 0; j < 4; ++j) {
          ah[m][j]     = (_Float16)v0[j];
          ah[m][j + 4] = (_Float16)v1[j];
        }
        if (split) {
#pragma unroll
          for (int j = 0; j < 4; ++j) {
            al[m][j]     = (_Float16)(v0[j] - (float)ah[m][j]);
            al[m][j + 4] = (_Float16)(v1[j] - (float)ah[m][j + 4]);
          }
        }
      }
    }
#pragma unroll
    for (int n = 0; n < 4; ++n) {
      const int row = wc * 64 + n * 16 + lr;
      const int sw = (row & 7) << 2;
      f32x4 v0 = *(const f32x4*)&Bs[row * 32 + ((lq * 8) ^ sw)];
      f32x4 v1 = *(const f32x4*)&Bs[row * 32 + ((lq * 8 + 4) ^ sw)];
#pragma unroll
      for (int j = 0; j < 4; ++j) {
        bh[n][j]     = (_Float16)v0[j];
        bh[n][j + 4] = (_Float16)v1[j];
      }
      if (split) {
#pragma unroll
        for (int j = 0; j < 4; ++j) {
          bl[n][j]     = (_Float16)(v0[j] - (float)bh[n][j]);
          bl[n][j + 4] = (_Float16)(v1[j] - (float)bh[n][j + 4]);
        }
      }
    }
#pragma unroll
    for (int m = 0; m < 4; ++m)
#pragma unroll
      for (int n = 0; n < 4; ++n) {
        acc[m][n] = __builtin_amdgcn_mfma_f32_16x16x32_f16(ah[m], bh[n], acc[m][n], 0, 0, 0);
        if (split) {
          acc[m][n] = __builtin_amdgcn_mfma_f32_16x16x32_f16(ah[m], bl[n], acc[m][n], 0, 0, 0);
          acc[m][n] = __builtin_amdgcn_mfma_f32_16x16x32_f16(al[m], bh[n], acc[m][n], 0, 0, 0);
        }
      }
  }

  float bv[4];
#pragma unroll
  for (int n = 0; n < 4; ++n) bv[n] = bias[bcol + wc * 64 + n * 16 + lr];

#pragma unroll
  for (int m = 0; m < 4; ++m)
#pragma unroll
    for (int n = 0; n < 4; ++n) {
      const int col = bcol + wc * 64 + n * 16 + lr;
#pragma unroll
      for (int j = 0; j < 4; ++j) {
        const int rowg = brow + wr * 64 + m * 16 + lq * 4 + j;
        const size_t idx = (size_t)rowg * 1024 + col;
        const float v = acc[m][n][j] + bv[n];
        if (op == 0)      outF[idx] = sigm(v);
        else if (op == 1) outF[idx] = tanhf(v);
        else if (op == 2) outH[idx] = (_Float16)sigm(v);
        else {
          const float hs = tanhf(v);
          const float hwv = hw_p[idx];
          const float hcv = hc_p[idx];
          outF[idx] = tanhf((1.0f - hwv) * hcv + hwv * hs);
        }
      }
    }
}

__global__ __launch_bounds__(256, 2)
void qurnn_gemm5(const float* inp, const float* hcur,
                 const float* Tr_w, const float* Tr_b,
                 const float* Wt_w, const float* Wt_b,
                 const float* Ei_w, const float* Ei_b,
                 const float* Wa_w, const float* Wa_b,
                 const float* Hw_w, const float* Hw_b,
                 float* out_tm, float* ws_ut, _Float16* ws_ei,
                 float* out_exc, float* out_h)
{
  switch (blockIdx.z) {
    case 0: gemm_core(inp, inp,  nullptr, Tr_w, Tr_b, 1024, true,  0, out_tm,  nullptr, nullptr, nullptr); break;
    case 1: gemm_core(inp, hcur, nullptr, Wt_w, Wt_b, 2048, true,  1, ws_ut,   nullptr, nullptr, nullptr); break;
    case 2: gemm_core(inp, inp,  nullptr, Ei_w, Ei_b, 1024, false, 2, nullptr, ws_ei,   nullptr, nullptr); break;
    case 3: gemm_core(inp, hcur, nullptr, Wa_w, Wa_b, 2048, false, 0, out_exc, nullptr, nullptr, nullptr); break;
    default:gemm_core(inp, hcur, nullptr, Hw_w, Hw_b, 2048, false, 0, out_h,   nullptr, nullptr, nullptr); break;
  }
}

__global__ __launch_bounds__(256)
void qurnn_cell(const f32x4* tc, const f32x4* ec, const f32x4* hc,
                const f32x4* ut, const half4* ei,
                f32x4* out_exc, f32x4* out_tm, half4* hup)
{
  const int i = blockIdx.x * 256 + threadIdx.x;   // exact grid: 4096 blocks
  const f32x4 tcv = tc[i], ecv = ec[i], hcv = hc[i];
  const f32x4 rav = out_tm[i];    // ratio parked in time-output region
  const f32x4 utv = ut[i];
  const f32x4 abv = out_exc[i];   // absorb parked in excited-output region
  const half4 eiv = ei[i];
  f32x4 to, eo; half4 ho;
#pragma unroll
  for (int j = 0; j < 4; ++j) {
    const float t = rav[j] * fmaxf(tcv[j] + utv[j], 0.0f) - 1.0f;
    const bool leap = (t <= 0.0f);
    to[j] = leap ? 0.0f : t;
    eo[j] = (leap ? 0.0f : ecv[j] + (float)eiv[j]) + abv[j];
    ho[j] = (_Float16)(leap ? hcv[j] * ecv[j] : 0.0f);
  }
  out_tm[i] = to;
  out_exc[i] = eo;
  hup[i] = ho;
}

__global__ __launch_bounds__(256, 2)
void qurnn_eh(const float* inp, const _Float16* hup,
              const float* Eh_w, const float* Eh_b,
              const float* hcur, float* out_h)
{
  gemm_core(inp, nullptr, hup, Eh_w, Eh_b, 2048, false, 3, out_h, nullptr, out_h, hcur);
}

extern "C" void kernel_launch(void* const* d_in, const int* in_sizes, int n_in,
                              void* d_out, int out_size, void* d_ws, size_t ws_size,
                              hipStream_t stream)
{
  const float* inp  = (const float*)d_in[0];
  const float* hcur = (const float*)d_in[1];
  const float* ec   = (const float*)d_in[2];
  const float* tc   = (const float*)d_in[3];
  const float* Wt_w = (const float*)d_in[4];
  const float* Wt_b = (const float*)d_in[5];
  const float* Wa_w = (const float*)d_in[6];
  const float* Wa_b = (const float*)d_in[7];
  const float* Eh_w = (const float*)d_in[8];
  const float* Eh_b = (const float*)d_in[9];
  const float* Hw_w = (const float*)d_in[10];
  const float* Hw_b = (const float*)d_in[11];
  const float* Tr_w = (const float*)d_in[12];
  const float* Tr_b = (const float*)d_in[13];
  const float* Ei_w = (const float*)d_in[14];
  const float* Ei_b = (const float*)d_in[15];

  float* out_h  = (float*)d_out;
  float* out_ex = out_h + NEL;
  float* out_tm = out_ex + NEL;

  float*    ws_ut  = (float*)d_ws;            // 16MB, leap-critical (f32)
  _Float16* ws_ei  = (_Float16*)(ws_ut + NEL);// 8MB
  _Float16* ws_hup = ws_ei + NEL;             // 8MB

  // Phase 1: Tr(split), Wt(split), Ei, Wa, Hw
  qurnn_gemm5<<<dim3(32, 8, 5), 256, 0, stream>>>(
      inp, hcur, Tr_w, Tr_b, Wt_w, Wt_b, Ei_w, Ei_b, Wa_w, Wa_b, Hw_w, Hw_b,
      out_tm, ws_ut, ws_ei, out_ex, out_h);

  // Phase 2: elementwise cell update
  qurnn_cell<<<dim3(4096), 256, 0, stream>>>(
      (const f32x4*)tc, (const f32x4*)ec, (const f32x4*)hcur,
      (const f32x4*)ws_ut, (const half4*)ws_ei,
      (f32x4*)out_ex, (f32x4*)out_tm, (half4*)ws_hup);

  // Phase 3: Eh GEMM on [input | h_up] + fused h_next epilogue
  qurnn_eh<<<dim3(32, 8), 256, 0, stream>>>(inp, ws_hup, Eh_w, Eh_b, hcur, out_h);
}

// Round 3
// 233.051 us; speedup vs baseline: 1.2936x; 1.2936x over previous
//
#include <hip/hip_runtime.h>
#include <math.h>

// QURNN cell, MI355X gfx950, f32 I/O. B=4096, D_IN=D_H=1024.
//
// Round 3: pre-convert all GEMM operands to f16 planes once (convert_k),
// then native-f16 m97-structure GEMMs (no inner-loop VALU conversion).
// Leap-critical GEMMs (Tr, Wt) use 2-way f16 split (hi+lo residual planes,
// 3 MFMAs: hh+hl+lh, ~1e-7 error); continuous GEMMs (Ei,Wa,Hw,Eh) use hi only.
//
// Dispatches: convert_k -> qurnn_gemm5 (z=Wt,Tr,Wa,Hw,Ei) -> qurnn_cell -> qurnn_eh
//
// ws (90MB): ut f32 [0,16M) | hup f16 [16,24M) | ei f16 [24,32M)
//   inpH [32,40) inpL [40,48) hcH [48,56) hcL [56,64)
//   WtH [64,68) WtL [68,72) TrH [72,74) TrL [74,76)
//   WaH [76,80) HwH [80,84) EhH [84,88) EiH [88,90)
// out-region parking: ratio->out_tm, absorb->out_ex, hw->out_h (all overwritten later).

typedef __attribute__((ext_vector_type(4))) float f32x4;
typedef __attribute__((ext_vector_type(8))) _Float16 half8;
typedef __attribute__((ext_vector_type(4))) _Float16 half4;

#define NEL (4096 * 1024)

__device__ __forceinline__ float sigm(float x) { return 1.0f / (1.0f + expf(-x)); }

__device__ __forceinline__ void gload16(const void* g, void* l) {
  __builtin_amdgcn_global_load_lds(
      (const __attribute__((address_space(1))) void*)g,
      (__attribute__((address_space(3))) void*)l, 16, 0, 0);
}

// OP: 0 sigmoid->f32, 1 tanh->f32, 2 sigmoid->f16, 3 h_next epilogue->f32
// sm: 32KB carve: AsH | BsH | AsL | BsL (4KB-elem each); AsL/BsL used iff SPLIT.
template <int OP, bool SPLIT>
__device__ __forceinline__ void gemm_body(
    _Float16* sm,
    const _Float16* A1h, const _Float16* A1l,
    const _Float16* A2h, const _Float16* A2l,
    const _Float16* Wh,  const _Float16* Wl,
    const float* bias, const int K,
    float* outF, _Float16* outH, const float* hw_p, const float* hc_p)
{
  _Float16* AsH = sm;
  _Float16* BsH = sm + 4096;
  _Float16* AsL = sm + 8192;
  _Float16* BsL = sm + 12288;
  const int tid = threadIdx.x;
  const int lane = tid & 63;
  const int w = tid >> 6;
  const int wr = w >> 1, wc = w & 1;       // 2x2 waves, 64x64 each
  const int brow = blockIdx.x * 128;
  const int bcol = blockIdx.y * 128;
  const int lr = lane & 15, lq = lane >> 4;
  const int r0 = tid >> 2;                 // staging row 0..63 (+64 for 2nd)
  const int cb = (tid & 3) * 8;            // 16B chunk (8 f16) within 64B row

  f32x4 acc[4][4] = {};

  for (int k0 = 0; k0 < K; k0 += 32) {
    const _Float16* Ah = (k0 < 1024) ? A1h : A2h;
    const _Float16* Al = (k0 < 1024) ? A1l : A2l;
    const int kk = k0 & 1023;
    __syncthreads();
    {
      const size_t ao  = (size_t)(brow + r0) * 1024 + kk + cb;
      const size_t ao2 = (size_t)(brow + r0 + 64) * 1024 + kk + cb;
      const size_t bo  = (size_t)(bcol + r0) * K + k0 + cb;
      const size_t bo2 = (size_t)(bcol + r0 + 64) * K + k0 + cb;
      gload16(Ah + ao,  &AsH[r0 * 32 + cb]);
      gload16(Ah + ao2, &AsH[(r0 + 64) * 32 + cb]);
      gload16(Wh + bo,  &BsH[r0 * 32 + cb]);
      gload16(Wh + bo2, &BsH[(r0 + 64) * 32 + cb]);
      if (SPLIT) {
        gload16(Al + ao,  &AsL[r0 * 32 + cb]);
        gload16(Al + ao2, &AsL[(r0 + 64) * 32 + cb]);
        gload16(Wl + bo,  &BsL[r0 * 32 + cb]);
        gload16(Wl + bo2, &BsL[(r0 + 64) * 32 + cb]);
      }
    }
    __syncthreads();

    half8 ah[4], bh[4], al[4], bl[4];
#pragma unroll
    for (int m = 0; m < 4; ++m) {
      const int row = wr * 64 + m * 16 + lr;
      ah[m] = *(const half8*)&AsH[row * 32 + lq * 8];
      if (SPLIT) al[m] = *(const half8*)&AsL[row * 32 + lq * 8];
    }
#pragma unroll
    for (int n = 0; n < 4; ++n) {
      const int row = wc * 64 + n * 16 + lr;
      bh[n] = *(const half8*)&BsH[row * 32 + lq * 8];
      if (SPLIT) bl[n] = *(const half8*)&BsL[row * 32 + lq * 8];
    }
#pragma unroll
    for (int m = 0; m < 4; ++m)
#pragma unroll
      for (int n = 0; n < 4; ++n) {
        acc[m][n] = __builtin_amdgcn_mfma_f32_16x16x32_f16(ah[m], bh[n], acc[m][n], 0, 0, 0);
        if (SPLIT) {
          acc[m][n] = __builtin_amdgcn_mfma_f32_16x16x32_f16(ah[m], bl[n], acc[m][n], 0, 0, 0);
          acc[m][n] = __builtin_amdgcn_mfma_f32_16x16x32_f16(al[m], bh[n], acc[m][n], 0, 0, 0);
        }
      }
  }

  float bv[4];
#pragma unroll
  for (int n = 0; n < 4; ++n) bv[n] = bias[bcol + wc * 64 + n * 16 + lr];

#pragma unroll
  for (int m = 0; m < 4; ++m)
#pragma unroll
    for (int n = 0; n < 4; ++n) {
      const int col = bcol + wc * 64 + n * 16 + lr;
#pragma unroll
      for (int j = 0; j < 4; ++j) {
        const int rowg = brow + wr * 64 + m * 16 + lq * 4 + j;
        const size_t idx = (size_t)rowg * 1024 + col;
        const float v = acc[m][n][j] + bv[n];
        if (OP == 0)      outF[idx] = sigm(v);
        else if (OP == 1) outF[idx] = tanhf(v);
        else if (OP == 2) outH[idx] = (_Float16)sigm(v);
        else {
          const float hs = tanhf(v);
          const float hwv = hw_p[idx];
          const float hcv = hc_p[idx];
          outF[idx] = tanhf((1.0f - hwv) * hcv + hwv * hs);
        }
      }
    }
}

// z: 0=Wt(split,K2048,tanh->ut) 1=Tr(split,K1024,sig->out_tm)
//    2=Wa(K2048,sig->out_ex) 3=Hw(K2048,sig->out_h) 4=Ei(K1024,sig->ei f16)
__global__ __launch_bounds__(256, 2)
void qurnn_gemm5(const _Float16* inpH, const _Float16* inpL,
                 const _Float16* hcH,  const _Float16* hcL,
                 const _Float16* WtH, const _Float16* WtL, const float* Wt_b,
                 const _Float16* TrH, const _Float16* TrL, const float* Tr_b,
                 const _Float16* WaH, const float* Wa_b,
                 const _Float16* HwH, const float* Hw_b,
                 const _Float16* EiH, const float* Ei_b,
                 float* ws_ut, float* out_tm, float* out_ex, float* out_h,
                 _Float16* ws_ei)
{
  __shared__ __align__(16) _Float16 sm[4 * 4096];   // 32KB
  switch (blockIdx.z) {
    case 0: gemm_body<1, true >(sm, inpH, inpL, hcH, hcL, WtH, WtL, Wt_b, 2048, ws_ut,  nullptr, nullptr, nullptr); break;
    case 1: gemm_body<0, true >(sm, inpH, inpL, nullptr, nullptr, TrH, TrL, Tr_b, 1024, out_tm, nullptr, nullptr, nullptr); break;
    case 2: gemm_body<0, false>(sm, inpH, nullptr, hcH, nullptr, WaH, nullptr, Wa_b, 2048, out_ex, nullptr, nullptr, nullptr); break;
    case 3: gemm_body<0, false>(sm, inpH, nullptr, hcH, nullptr, HwH, nullptr, Hw_b, 2048, out_h,  nullptr, nullptr, nullptr); break;
    default:gemm_body<2, false>(sm, inpH, nullptr, nullptr, nullptr, EiH, nullptr, Ei_b, 1024, nullptr, ws_ei, nullptr, nullptr); break;
  }
}

__global__ __launch_bounds__(256, 2)
void qurnn_eh(const _Float16* inpH, const _Float16* hup,
              const _Float16* EhH, const float* Eh_b,
              const float* hcur, float* out_h)
{
  __shared__ __align__(16) _Float16 sm[2 * 4096];   // 16KB (non-split)
  gemm_body<3, false>(sm, inpH, nullptr, hup, nullptr, EhH, nullptr, Eh_b, 2048,
                      out_h, nullptr, out_h, hcur);
}

__global__ __launch_bounds__(256)
void qurnn_cell(const f32x4* tc, const f32x4* ec, const f32x4* hc,
                const f32x4* ut, const half4* ei,
                f32x4* out_ex, f32x4* out_tm, half4* hup)
{
  const int i = blockIdx.x * 256 + threadIdx.x;   // exact: 4096 blocks
  const f32x4 tcv = tc[i], ecv = ec[i], hcv = hc[i];
  const f32x4 rav = out_tm[i];    // ratio parked in time-out region
  const f32x4 utv = ut[i];
  const f32x4 abv = out_ex[i];    // absorb parked in excited-out region
  const half4 eiv = ei[i];
  f32x4 to, eo; half4 ho;
#pragma unroll
  for (int j = 0; j < 4; ++j) {
    const float t = rav[j] * fmaxf(tcv[j] + utv[j], 0.0f) - 1.0f;
    const bool leap = (t <= 0.0f);
    to[j] = leap ? 0.0f : t;
    eo[j] = (leap ? 0.0f : ecv[j] + (float)eiv[j]) + abv[j];
    ho[j] = (_Float16)(leap ? hcv[j] * ecv[j] : 0.0f);
  }
  out_tm[i] = to;
  out_ex[i] = eo;
  hup[i] = ho;
}

// z-segment conversion: hi (+ optional lo residual) f16 planes
__global__ __launch_bounds__(256)
void convert_k(const float* inp, const float* hcur,
               const float* Wt_w, const float* Tr_w, const float* Wa_w,
               const float* Hw_w, const float* Eh_w, const float* Ei_w,
               _Float16* inpH, _Float16* inpL, _Float16* hcH, _Float16* hcL,
               _Float16* WtH, _Float16* WtL, _Float16* TrH, _Float16* TrL,
               _Float16* WaH, _Float16* HwH, _Float16* EhH, _Float16* EiH)
{
  const float* src; _Float16* dh; _Float16* dl; int n4;
  switch (blockIdx.z) {
    case 0: src = inp;  dh = inpH; dl = inpL; n4 = NEL / 4;     break;
    case 1: src = hcur; dh = hcH;  dl = hcL;  n4 = NEL / 4;     break;
    case 2: src = Wt_w; dh = WtH;  dl = WtL;  n4 = (1024*2048)/4; break;
    case 3: src = Tr_w; dh = TrH;  dl = TrL;  n4 = (1024*1024)/4; break;
    case 4: src = Wa_w; dh = WaH;  dl = nullptr; n4 = (1024*2048)/4; break;
    case 5: src = Hw_w; dh = HwH;  dl = nullptr; n4 = (1024*2048)/4; break;
    case 6: src = Eh_w; dh = EhH;  dl = nullptr; n4 = (1024*2048)/4; break;
    default:src = Ei_w; dh = EiH;  dl = nullptr; n4 = (1024*1024)/4; break;
  }
  for (int i = blockIdx.x * 256 + threadIdx.x; i < n4; i += gridDim.x * 256) {
    const f32x4 v = ((const f32x4*)src)[i];
    half4 h, l;
#pragma unroll
    for (int j = 0; j < 4; ++j) {
      h[j] = (_Float16)v[j];
      l[j] = (_Float16)(v[j] - (float)h[j]);
    }
    ((half4*)dh)[i] = h;
    if (dl) ((half4*)dl)[i] = l;
  }
}

extern "C" void kernel_launch(void* const* d_in, const int* in_sizes, int n_in,
                              void* d_out, int out_size, void* d_ws, size_t ws_size,
                              hipStream_t stream)
{
  const float* inp  = (const float*)d_in[0];
  const float* hcur = (const float*)d_in[1];
  const float* ec   = (const float*)d_in[2];
  const float* tc   = (const float*)d_in[3];
  const float* Wt_w = (const float*)d_in[4];
  const float* Wt_b = (const float*)d_in[5];
  const float* Wa_w = (const float*)d_in[6];
  const float* Wa_b = (const float*)d_in[7];
  const float* Eh_w = (const float*)d_in[8];
  const float* Eh_b = (const float*)d_in[9];
  const float* Hw_w = (const float*)d_in[10];
  const float* Hw_b = (const float*)d_in[11];
  const float* Tr_w = (const float*)d_in[12];
  const float* Tr_b = (const float*)d_in[13];
  const float* Ei_w = (const float*)d_in[14];
  const float* Ei_b = (const float*)d_in[15];

  float* out_h  = (float*)d_out;
  float* out_ex = out_h + NEL;
  float* out_tm = out_ex + NEL;

  char* wsb = (char*)d_ws;
  float*    ws_ut  = (float*)(wsb);
  _Float16* ws_hup = (_Float16*)(wsb + (16u << 20));
  _Float16* ws_ei  = (_Float16*)(wsb + (24u << 20));
  _Float16* inpH   = (_Float16*)(wsb + (32u << 20));
  _Float16* inpL   = (_Float16*)(wsb + (40u << 20));
  _Float16* hcH    = (_Float16*)(wsb + (48u << 20));
  _Float16* hcL    = (_Float16*)(wsb + (56u << 20));
  _Float16* WtH    = (_Float16*)(wsb + (64u << 20));
  _Float16* WtL    = (_Float16*)(wsb + (68u << 20));
  _Float16* TrH    = (_Float16*)(wsb + (72u << 20));
  _Float16* TrL    = (_Float16*)(wsb + (74u << 20));
  _Float16* WaH    = (_Float16*)(wsb + (76u << 20));
  _Float16* HwH    = (_Float16*)(wsb + (80u << 20));
  _Float16* EhH    = (_Float16*)(wsb + (84u << 20));
  _Float16* EiH    = (_Float16*)(wsb + (88u << 20));  // end 90MB

  // Phase 0: f32 -> f16 hi/lo planes
  convert_k<<<dim3(512, 1, 8), 256, 0, stream>>>(
      inp, hcur, Wt_w, Tr_w, Wa_w, Hw_w, Eh_w, Ei_w,
      inpH, inpL, hcH, hcL, WtH, WtL, TrH, TrL, WaH, HwH, EhH, EiH);

  // Phase 1: 5 GEMMs, heavy (Wt split) first
  qurnn_gemm5<<<dim3(32, 8, 5), 256, 0, stream>>>(
      inpH, inpL, hcH, hcL, WtH, WtL, Wt_b, TrH, TrL, Tr_b,
      WaH, Wa_b, HwH, Hw_b, EiH, Ei_b,
      ws_ut, out_tm, out_ex, out_h, ws_ei);

  // Phase 2: elementwise cell update
  qurnn_cell<<<dim3(4096), 256, 0, stream>>>(
      (const f32x4*)tc, (const f32x4*)ec, (const f32x4*)hcur,
      (const f32x4*)ws_ut, (const half4*)ws_ei,
      (f32x4*)out_ex, (f32x4*)out_tm, (half4*)ws_hup);

  // Phase 3: Eh GEMM on [inp | h_up] + fused h_next epilogue
  qurnn_eh<<<dim3(32, 8), 256, 0, stream>>>(inpH, ws_hup, EhH, Eh_b, hcur, out_h);
}